// Round 3
// baseline (353.710 us; speedup 1.0000x reference)
//
#include <hip/hip_runtime.h>
#include <stdint.h>

// ---------------------------------------------------------------------------
// Transformer block: LN1 -> QKV GEMM (routes Q*scale / kT / vd) -> v_transpose
// -> flash attention (static-max softmax, fat waves + in-block key-split) ->
// proj(+res) -> LN2 -> MLP1(GELU) -> MLP2(+res). bf16 MFMA 16x16x32, fp32 acc.
// Fragment layouts (learn_hip m89/m91):
//   A-frag:  A[m = lane&15][k = (lane>>4)*8 + j]
//   B-frag:  B[k = (lane>>4)*8 + j][n = lane&15]  (= Bt[n][k])
//   C/D   :  D[m = (lane>>4)*4 + r][n = lane&15]
// R10: de-clobbered the 8-phase pipeline. R1/R2 wrote every phase fence as
// asm volatile(:::"memory"); the waitcnt pass treats memory-clobber asm as
// a potential reader of DMA-written LDS and inserted s_waitcnt vmcnt(0)
// before EACH fence -> full drain per phase -> T4 nullified -> gemm_bt-level
// perf both rounds. Now: (a) fences are sched_barrier(0) + raw s_barrier +
// clobber-free s_waitcnt asm (template-exact, m201); (b) frag loads are
// inline-asm ds_read_b128 on AS(3) addresses -> no compiler-visible LDS
// reads in the loop -> the ONLY vmcnt gates are the hand-placed counted
// waits (vmcnt(8) at P4/P8, vmcnt(0) only in the tail). Region safety:
// BsX last read P2, staged P3; AsX last read P3, staged P4; all-waves
// read-completion guaranteed by bar_mid's lgkmcnt(0) + the following
// phase-end barrier before any staging wave can issue its DMA.
// proj + MLP2 stay on gemm_bt (N=1024 -> 256^2 grid would be 64 blocks).
// ---------------------------------------------------------------------------

#define DIMC 1024
#define HIDN 4096
#define SEQ  2048
#define TOK  4096   // B*N = 2*2048

typedef __bf16 bf16x8 __attribute__((ext_vector_type(8)));
typedef float  f32x4  __attribute__((ext_vector_type(4)));
typedef unsigned short ushort8 __attribute__((ext_vector_type(8)));

__device__ inline unsigned short f2bf(float f) {
  union { float f; unsigned u; } v; v.f = f;
  unsigned u = v.u;
  return (unsigned short)((u + 0x7fffu + ((u >> 16) & 1u)) >> 16);  // RNE
}

// HW packed fp32->bf16 (CDNA3+): lo = cvt(a), hi = cvt(b)
__device__ inline unsigned cvt_pk_bf16(float a, float b) {
  unsigned r;
  asm("v_cvt_pk_bf16_f32 %0, %1, %2" : "=v"(r) : "v"(a), "v"(b));
  return r;
}

#if __has_builtin(__builtin_amdgcn_exp2f)
__device__ inline float fast_exp2(float x) { return __builtin_amdgcn_exp2f(x); }
#else
__device__ inline float fast_exp2(float x) { return exp2f(x); }
#endif

__device__ inline f32x4 mfma_bf16(bf16x8 a, bf16x8 b, f32x4 c) {
  return __builtin_amdgcn_mfma_f32_16x16x32_bf16(a, b, c, 0, 0, 0);
}

// async global->LDS, 16B per lane; LDS dest = wave-uniform base + lane*16
typedef const __attribute__((address_space(1))) unsigned int* as1_u32p;
typedef __attribute__((address_space(3))) unsigned int* as3_u32p;
__device__ inline void gload_lds16(const unsigned short* g, unsigned short* l) {
  __builtin_amdgcn_global_load_lds((as1_u32p)(const void*)g, (as3_u32p)(void*)l,
                                   16, 0, 0);
}

// Inline-asm LDS read, invisible to the waitcnt pass (no auto vmcnt/lgkmcnt
// insertion vs in-flight global_load_lds DMAs). Completion is enforced ONLY
// by the explicit lgkmcnt(0)+sched_barrier in bar_mid (rule #18).
typedef const __attribute__((address_space(3))) unsigned short* as3_cu16p;
__device__ inline bf16x8 ds_read128(const unsigned short* p) {
  bf16x8 r;
  unsigned off = (unsigned)(size_t)(as3_cu16p)(const void*)p;
  asm volatile("ds_read_b128 %0, %1" : "=v"(r) : "v"(off));
  return r;
}

// Phase-start boundary: raw barrier, then wait this wave's ds_reads, then pin
// the scheduler so MFMAs aren't hoisted above the wait (rule #18).
// NO memory clobbers anywhere: a clobber makes the waitcnt pass treat the asm
// as a reader of DMA-written LDS and drain vmcnt(0) (the R1/R2 bug).
__device__ inline void bar_mid() {
  __builtin_amdgcn_sched_barrier(0);
  __builtin_amdgcn_s_barrier();
  asm volatile("s_waitcnt lgkmcnt(0)");
  __builtin_amdgcn_sched_barrier(0);
}
// Phase-end boundary.
__device__ inline void bar_end() {
  __builtin_amdgcn_sched_barrier(0);
  __builtin_amdgcn_s_barrier();
  __builtin_amdgcn_sched_barrier(0);
}

// ---------------------------------------------------------------------------
// All 4 weight transposes in one launch: w[K][N] fp32 -> wt[N][K] bf16
// ---------------------------------------------------------------------------
__global__ __launch_bounds__(256)
void transpose_cast4(const float* __restrict__ wa, unsigned short* __restrict__ ta,
                     const float* __restrict__ wb, unsigned short* __restrict__ tb,
                     const float* __restrict__ wc, unsigned short* __restrict__ tc,
                     const float* __restrict__ wd, unsigned short* __restrict__ td) {
  __shared__ float tile[32][33];
  const int bid = blockIdx.x;
  const float* w; unsigned short* wt; int K, N, bx, by;
  if (bid < 3072)      { w = wa; wt = ta; K = 1024; N = 3072; bx = bid % 96;  by = bid / 96; }
  else if (bid < 4096) { int i = bid - 3072; w = wb; wt = tb; K = 1024; N = 1024; bx = i % 32;  by = i / 32; }
  else if (bid < 8192) { int i = bid - 4096; w = wc; wt = tc; K = 1024; N = 4096; bx = i % 128; by = i / 128; }
  else                 { int i = bid - 8192; w = wd; wt = td; K = 4096; N = 1024; bx = i % 32;  by = i / 32; }
  const int k0 = by * 32;
  const int n0 = bx * 32;
  const int tx = threadIdx.x & 31;
  const int ty = threadIdx.x >> 5;  // 0..7
#pragma unroll
  for (int i = 0; i < 4; i++)
    tile[ty + i * 8][tx] = w[(size_t)(k0 + ty + i * 8) * N + n0 + tx];
  __syncthreads();
#pragma unroll
  for (int i = 0; i < 4; i++)
    wt[(size_t)(n0 + ty + i * 8) * K + k0 + tx] = f2bf(tile[tx][ty + i * 8]);
}

// ---------------------------------------------------------------------------
// LayerNorm: x[rows][1024] fp32 -> out bf16
// ---------------------------------------------------------------------------
__global__ __launch_bounds__(256)
void ln_kernel(const float* __restrict__ x, const float* __restrict__ g,
               const float* __restrict__ b, unsigned short* __restrict__ out) {
  const int row = blockIdx.x;
  const int tid = threadIdx.x;
  const float4* xr = (const float4*)&x[(size_t)row * DIMC];
  float4 v = xr[tid];
  float s  = v.x + v.y + v.z + v.w;
  float sq = v.x * v.x + v.y * v.y + v.z * v.z + v.w * v.w;
#pragma unroll
  for (int off = 32; off > 0; off >>= 1) {
    s  += __shfl_xor(s, off, 64);
    sq += __shfl_xor(sq, off, 64);
  }
  __shared__ float red[8];
  if ((tid & 63) == 0) { red[tid >> 6] = s; red[4 + (tid >> 6)] = sq; }
  __syncthreads();
  s  = red[0] + red[1] + red[2] + red[3];
  sq = red[4] + red[5] + red[6] + red[7];
  const float mu  = s * (1.0f / DIMC);
  const float var = sq * (1.0f / DIMC) - mu * mu;
  const float rs  = rsqrtf(var + 1e-5f);
  const int c = tid * 4;
  float vv[4] = {v.x, v.y, v.z, v.w};
#pragma unroll
  for (int j = 0; j < 4; j++)
    out[(size_t)row * DIMC + c + j] = f2bf((vv[j] - mu) * rs * g[c + j] + b[c + j]);
}

// ---------------------------------------------------------------------------
// gemm256: C[M=4096][N] = A @ B, Bt[N][K] bf16. 256x256 tile, BK=64, 8 waves
// (2M x 4N, per-wave 128x64 output = acc[8][4] f32x4). LDS 128 KiB as FOUR
// statically distinct buffers As0/Bs0/As1/Bs1 [256][64] (XOR chunk swizzle
// phys = log ^ (row&7), applied on the global-source side of the linear
// global_load_lds write). 8 phases / 2 K-tiles per iteration; per K-tile in
// buffer X: P1{ldA(mh0),ldB(nh0) | MM(0,0)} P2{ldB(nh1) | MM(0,1)}
// P3{ldA(mh1), stage B(t+2)->BsX | MM(1,1)} P4{stage A(t+2)->AsX | MM(1,0)}.
// s_waitcnt vmcnt(8) ONLY at phases 4 and 8 (keeps the next tile's 8 DMAs in
// flight across barriers); never 0 in the main loop. All frag loads are
// inline-asm ds_read_b128 -> zero compiler-visible LDS reads -> zero
// compiler-inserted vmcnt waits. Grid 1D = GX*16, bid&7 -> XCD, 2 stripes.
// EPI: 0 = QKV routing (Q*scale->qd, K->kTd, V->vd); 2 = gelu(+bias) bf16.
// ---------------------------------------------------------------------------
template <int EPI, int N, int K, int GX>
__global__ __launch_bounds__(512, 2)
void gemm256(const unsigned short* __restrict__ A,
             const unsigned short* __restrict__ Bt,
             unsigned short* __restrict__ Cb,
             const float* __restrict__ bias,
             unsigned short* __restrict__ qd,
             unsigned short* __restrict__ kTd,
             unsigned short* __restrict__ vd) {
  constexpr int KT = K >> 6;                 // K-tiles
  static_assert((KT & 1) == 0 && KT >= 4, "KT must be even, >=4");
  __shared__ unsigned short As0[256 * 64];   // 32 KiB each
  __shared__ unsigned short Bs0[256 * 64];
  __shared__ unsigned short As1[256 * 64];
  __shared__ unsigned short Bs1[256 * 64];
  const int bid = blockIdx.x;
  const int xcd = bid & 7;
  const int lin = bid >> 3;
  const int bx  = lin % GX;
  const int by  = (xcd << 1) + lin / GX;     // 2 y-stripes per XCD (gy=16)
  const int tid  = threadIdx.x;              // 0..511
  const int lane = tid & 63;
  const int wave = tid >> 6;                 // 0..7
  const int m0 = by * 256;
  const int n0 = bx * 256;
  const int wm = (wave >> 2) * 128;          // wave's A-row base in tile
  const int wn = (wave & 3) * 64;            // wave's B-row base in tile
  const int lm = lane & 15;
  const int lg = lane >> 4;
  // staging: thread covers row r8 (of a 64-row pass), chunk c8, swizzled src
  const int r8 = tid >> 3;                   // 0..63
  const int c8 = tid & 7;
  const int csrc = (c8 ^ (r8 & 7)) * 8;
  const unsigned short* gA0 = &A [(size_t)(m0 + r8) * K + csrc];
  const unsigned short* gB0 = &Bt[(size_t)(n0 + r8) * K + csrc];
  const int ldsb = wave * 512;               // wave-uniform LDS base (shorts)
  // frag read phys offsets (swizzle inverse): chunk = (sub*4+lg) ^ (lm&7)
  const int xo0 = ((lg)     ^ (lm & 7)) * 8;
  const int xo1 = ((4 + lg) ^ (lm & 7)) * 8;

  f32x4 acc[8][4];
#pragma unroll
  for (int i = 0; i < 8; i++)
#pragma unroll
    for (int j = 0; j < 4; j++) acc[i][j] = {0.f, 0.f, 0.f, 0.f};
  bf16x8 af[4][2];          // current A half: 4 m-frags x 2 k-subs
  bf16x8 b0r[2][2];         // B half nh0 (lives P1..P4)
  bf16x8 b1r[2][2];         // B half nh1 (lives P2..P3)

  auto LDA = [&](const unsigned short* buf, const int mh) {
#pragma unroll
    for (int mt = 0; mt < 4; ++mt) {
      const int row = wm + mh * 64 + mt * 16 + lm;
      af[mt][0] = ds_read128(&buf[row * 64 + xo0]);
      af[mt][1] = ds_read128(&buf[row * 64 + xo1]);
    }
  };
  auto LDB = [&](const unsigned short* buf, const int nh, bf16x8 (&br)[2][2]) {
#pragma unroll
    for (int nt = 0; nt < 2; ++nt) {
      const int row = wn + nh * 32 + nt * 16 + lm;
      br[nt][0] = ds_read128(&buf[row * 64 + xo0]);
      br[nt][1] = ds_read128(&buf[row * 64 + xo1]);
    }
  };
  auto MM = [&](const int mh, const int nh, bf16x8 (&br)[2][2]) {
    __builtin_amdgcn_s_setprio(1);
#pragma unroll
    for (int mt = 0; mt < 4; ++mt)
#pragma unroll
      for (int nt = 0; nt < 2; ++nt) {
        acc[mh * 4 + mt][nh * 2 + nt] =
            mfma_bf16(af[mt][0], br[nt][0], acc[mh * 4 + mt][nh * 2 + nt]);
        acc[mh * 4 + mt][nh * 2 + nt] =
            mfma_bf16(af[mt][1], br[nt][1], acc[mh * 4 + mt][nh * 2 + nt]);
      }
    __builtin_amdgcn_s_setprio(0);
  };
  auto STGA = [&](unsigned short* buf, const int kt) {
#pragma unroll
    for (int q = 0; q < 4; ++q)
      gload_lds16(gA0 + (size_t)(q * 64) * K + kt * 64, &buf[q * 4096 + ldsb]);
  };
  auto STGB = [&](unsigned short* buf, const int kt) {
#pragma unroll
    for (int q = 0; q < 4; ++q)
      gload_lds16(gB0 + (size_t)(q * 64) * K + kt * 64, &buf[q * 4096 + ldsb]);
  };
  // One K-tile = 4 phases. skt >= 0: stage tile skt into sA/sB.
  // wmode: 8 -> vmcnt(8) at P4 end; 0 -> vmcnt(0); -1 -> none.
  auto QUAD = [&](const unsigned short* AS, const unsigned short* BS,
                  unsigned short* sA, unsigned short* sB, const int skt,
                  const int wmode) {
    // P1
    LDA(AS, 0); LDB(BS, 0, b0r);
    bar_mid(); MM(0, 0, b0r); bar_end();
    // P2
    LDB(BS, 1, b1r);
    bar_mid(); MM(0, 1, b1r); bar_end();
    // P3  (BS fully read by end of P2 -> safe to stage into it)
    LDA(AS, 1);
    if (skt >= 0) STGB(sB, skt);
    bar_mid(); MM(1, 1, b1r); bar_end();
    // P4  (AS fully read by end of P3 -> safe to stage into it)
    if (skt >= 0) STGA(sA, skt);
    bar_mid(); MM(1, 0, b0r);
    if (wmode == 8)      asm volatile("s_waitcnt vmcnt(8)");
    else if (wmode == 0) asm volatile("s_waitcnt vmcnt(0)");
    bar_end();
  };

  // prologue: tile0 -> buf0, tile1 -> buf1; wait tile0 (leave tile1 in flight)
  STGA(As0, 0); STGB(Bs0, 0);
  STGA(As1, 1); STGB(Bs1, 1);
  asm volatile("s_waitcnt vmcnt(8)");
  bar_end();

#pragma unroll 1
  for (int i = 0; i < KT / 2 - 1; ++i) {
    QUAD(As0, Bs0, As0, Bs0, 2 * i + 2, 8);   // tile 2i   from buf0
    QUAD(As1, Bs1, As1, Bs1, 2 * i + 3, 8);   // tile 2i+1 from buf1
  }
  QUAD(As0, Bs0, nullptr, nullptr, -1, 0);     // tile KT-2 (drain tile KT-1)
  QUAD(As1, Bs1, nullptr, nullptr, -1, -1);    // tile KT-1

  // ---- epilogue ----
#pragma unroll
  for (int mt = 0; mt < 8; ++mt) {
    const int row = m0 + wm + mt * 16 + lg * 4;
#pragma unroll
    for (int nt = 0; nt < 4; ++nt) {
      const int col = n0 + wn + nt * 16 + lm;
#pragma unroll
      for (int r = 0; r < 4; ++r) {
        float v = acc[mt][nt][r];
        if (EPI == 0) {
          const int rr = row + r;
          const int bb = rr >> 11, key = rr & (SEQ - 1);
          if (col < 1024) {
            qd[(size_t)rr * 1024 + col] = f2bf(v * 0.18033688011112042f);
          } else if (col < 2048) {
            const int d = col - 1024, h = d >> 6, dd = d & 63;
            kTd[(((size_t)(bb * 16 + h)) * SEQ + key) * 64 + dd] = f2bf(v);
          } else {
            vd[(size_t)(row + r) * 1024 + (col - 2048)] = f2bf(v);
          }
        } else {
          float xg = v + bias[col];
          Cb[(size_t)(row + r) * N + col] =
              f2bf(0.5f * xg * (1.0f + erff(xg * 0.70710678118654752f)));
        }
      }
    }
  }
}

// ---------------------------------------------------------------------------
// GEMM: C[M][N] = A[M][K] @ B, Bt[N][K] bf16. 128xTN tile, BK=64, 4 waves.
// 1D grid, XCD decode: bid&7 = XCD owns 4 consecutive y-stripes.
// EPI: 1 = +bias+res fp32; 2 = gelu(+bias) bf16   (used for proj / MLP2)
// ---------------------------------------------------------------------------
template <int EPI, int TN>
__global__ __launch_bounds__(256, (TN == 64) ? 4 : 3)
void gemm_bt(const unsigned short* __restrict__ A,
             const unsigned short* __restrict__ Bt,
             float* __restrict__ Cf, unsigned short* __restrict__ Cb,
             const float* __restrict__ bias, const float* __restrict__ res,
             int M, int N, int K) {
  constexpr int NU = TN / 32;            // B n-tiles per wave
  constexpr int BP = TN / 32;            // B staging passes (32 rows each)
  __shared__ unsigned short As[128 * 64];
  __shared__ unsigned short Bs[TN * 64];
  const int gx  = N / TN;                // x-tiles; gy = M/128 = 32 always
  const int bid = blockIdx.x;
  const int xcd = bid & 7;
  const int lin = bid >> 3;
  const int bx  = lin % gx;
  const int by  = (xcd << 2) + lin / gx;  // 4 y-stripes per XCD
  const int tid  = threadIdx.x;
  const int lane = tid & 63;
  const int wave = tid >> 6;
  const int m0 = by * 128;
  const int n0 = bx * TN;
  const int wm = (wave >> 1) * 64;
  const int wn = (wave & 1) * (TN / 2);
  const int lm = lane & 15;
  const int lg = lane >> 4;
  const int r8 = tid >> 3;     // 0..31 row within pass
  const int c8 = tid & 7;      // phys 16B chunk within 128B row
  const int csrc = ((c8 ^ (r8 & 7)) * 8);  // logical elem offset (swizzled)

  const unsigned short* gA = &A [(size_t)(m0 + r8) * K + csrc];
  const unsigned short* gB = &Bt[(size_t)(n0 + r8) * K + csrc];

  f32x4 acc[4][NU];
#pragma unroll
  for (int t = 0; t < 4; t++)
#pragma unroll
    for (int u = 0; u < NU; u++) acc[t][u] = {0.f, 0.f, 0.f, 0.f};

  const int x0 = (lg ^ (lm & 7)) * 8;        // sub 0 phys chunk offset (elems)
  const int x1 = ((4 + lg) ^ (lm & 7)) * 8;  // sub 1

  for (int k0 = 0; k0 < K; k0 += 64) {
    __syncthreads();                 // prior tile's LDS reads done
#pragma unroll
    for (int p = 0; p < 4; p++)
      gload_lds16(gA + (size_t)p * 32 * K + k0, &As[p * 2048 + wave * 512]);
#pragma unroll
    for (int p = 0; p < BP; p++)
      gload_lds16(gB + (size_t)p * 32 * K + k0, &Bs[p * 2048 + wave * 512]);
    __syncthreads();                 // drains vmcnt before barrier
#pragma unroll
    for (int sub = 0; sub < 2; sub++) {
      const int xo = sub ? x1 : x0;
      bf16x8 af[4], bfr[NU];
#pragma unroll
      for (int t = 0; t < 4; t++)  af[t]  = *(const bf16x8*)&As[(wm + t * 16 + lm) * 64 + xo];
#pragma unroll
      for (int u = 0; u < NU; u++) bfr[u] = *(const bf16x8*)&Bs[(wn + u * 16 + lm) * 64 + xo];
#pragma unroll
      for (int t = 0; t < 4; t++)
#pragma unroll
        for (int u = 0; u < NU; u++)
          acc[t][u] = mfma_bf16(af[t], bfr[u], acc[t][u]);
    }
  }

#pragma unroll
  for (int t = 0; t < 4; t++) {
    const int row = m0 + wm + t * 16 + lg * 4;
#pragma unroll
    for (int u = 0; u < NU; u++) {
      const int col = n0 + wn + u * 16 + lm;
#pragma unroll
      for (int r = 0; r < 4; r++) {
        float v = acc[t][u][r];
        size_t idx = (size_t)(row + r) * N + col;
        if (EPI == 1) {
          Cf[idx] = v + bias[col] + res[idx];
        } else {
          float xg = v + bias[col];
          Cb[idx] = f2bf(0.5f * xg * (1.0f + erff(xg * 0.70710678118654752f)));
        }
      }
    }
  }
}

// ---------------------------------------------------------------------------
// V transpose per head: vd[token][1024] -> vT[bh][d][key] (via LDS)
// ---------------------------------------------------------------------------
__global__ __launch_bounds__(256)
void v_transpose(const unsigned short* __restrict__ vd,
                 unsigned short* __restrict__ vT) {
  const int kt = blockIdx.x;
  const int bh = blockIdx.y;
  const int b = bh >> 4, h = bh & 15;
  const int tid = threadIdx.x;
  __shared__ unsigned short tile[64 * 72];
  const int tok = tid >> 2;       // 0..63
  const int ch  = tid & 3;        // chunks ch, ch+4 (8 d each)
  const size_t srow = (size_t)(b * SEQ + kt * 64 + tok) * 1024 + h * 64;
  ushort8 va = *(const ushort8*)&vd[srow + ch * 8];
  ushort8 vb = *(const ushort8*)&vd[srow + 32 + ch * 8];
  *(ushort8*)&tile[tok * 72 + ch * 8] = va;
  *(ushort8*)&tile[tok * 72 + 32 + ch * 8] = vb;
  __syncthreads();
  const int d = tid >> 2;         // 0..63
  ushort8 o0, o1;
#pragma unroll
  for (int j = 0; j < 8; j++) {
    o0[j] = tile[(ch * 8 + j) * 72 + d];
    o1[j] = tile[((ch + 4) * 8 + j) * 72 + d];
  }
  const size_t vdst = ((size_t)bh * 64 + d) * SEQ + kt * 64;
  *(ushort8*)&vT[vdst + ch * 8] = o0;
  *(ushort8*)&vT[vdst + 32 + ch * 8] = o1;
}

// ---------------------------------------------------------------------------
// Flash attention: fat waves + in-block key-split, static-max softmax.
// Block = 256 thr = 4 waves; wave w: ks = w>>1 (keys ks*1024..+1023),
// qh = w&1 (64 q-rows, 4 sets). 16-tile k-loop. After the loop, ks=1 waves
// export o/li via LDS; ks=0 waves add (exactly additive: fixed max) and
// store. Grid 512 (bid&7=XCD -> 4 bh/XCD, kT/vT L2-resident). LDS 64 KB.
// ---------------------------------------------------------------------------
__global__ __launch_bounds__(256, 2)
void attn_kernel(const unsigned short* __restrict__ qbuf,
                 const unsigned short* __restrict__ kT,
                 const unsigned short* __restrict__ vT,
                 unsigned short* __restrict__ out) {
  const int bid = blockIdx.x;
  const int xcd = bid & 7;
  const int lin = bid >> 3;                 // 0..63
  const int bh  = (xcd << 2) + (lin >> 4);  // 4 bh per XCD
  const int qt  = lin & 15;                 // 128-q tile
  const int b  = bh >> 4;
  const int h  = bh & 15;
  const int tid  = threadIdx.x;             // 0..255
  const int lane = tid & 63;
  const int wave = tid >> 6;                // 0..3
  const int ks   = wave >> 1;               // key split
  const int qh   = wave & 1;                // q half
  const int lm = lane & 15;
  const int lg = lane >> 4;

  __shared__ f32x4 shbuf[4096];             // 64 KB, multi-purpose
  unsigned short* Ks = (unsigned short*)shbuf;          // [2][64*64]
  unsigned short* Vs = (unsigned short*)shbuf + 8192;   // [2][64*64]
  unsigned short* Ps = (unsigned short*)shbuf + 16384;  // [4][64*64]

  const int qrow_base = b * SEQ + qt * 128 + qh * 64;
  bf16x8 qb[4][2];  // [set][khalf] B-frag: Q natural (pre-scaled)
#pragma unroll
  for (int s = 0; s < 4; s++)
#pragma unroll
    for (int c = 0; c < 2; c++)
      qb[s][c] = *(const bf16x8*)&qbuf[(size_t)(qrow_base + s * 16 + lm) * 1024 +
                                       h * 64 + c * 32 + lg * 8];

  f32x4 o[4][4];   // [dtile][set]: m = d, n = q
#pragma unroll
  for (int dt = 0; dt < 4; dt++)
#pragma unroll
    for (int s = 0; s < 4; s++) o[dt][s] = {0.f, 0.f, 0.f, 0.f};
  float li[4] = {0.f, 0.f, 0.f, 0.f};

  const unsigned short* kbp = &kT[(size_t)bh * SEQ * 64];
  const unsigned short* vbp = &vT[(size_t)bh * 64 * SEQ];
  const int ts   = tid & 127;                     // id within split pair
  const int srow = ts >> 3;                       // 0..15 (row within pass)
  const int slog = ((ts & 7) ^ (srow & 7)) * 8;   // swizzled source offset
  const int koff = ks * 1024;                     // split key base
  const int xk0 = ((lg)     ^ (lm & 7)) * 8;      // frag phys offsets
  const int xk1 = ((4 + lg) ^ (lm & 7)) * 8;
  unsigned short* ksb = Ks + ks * 4096;
  unsigned short* vsb = Vs + ks * 4096;
  unsigned short* psb = Ps + wave * 4096;
  unsigned short* kdst = ksb + ((ts >> 6) * 512); // wave-uniform + lane*16
  unsigned short* vdst = vsb + ((ts >> 6) * 512);

  for (int kt = 0; kt < 16; kt++) {
    __syncthreads();   // prior tile's frag reads done
#pragma unroll
    for (int p = 0; p < 4; p++) {
      gload_lds16(&kbp[(size_t)(koff + kt * 64 + p * 16 + srow) * 64 + slog],
                  kdst + p * 1024);
      gload_lds16(&vbp[(size_t)(p * 16 + srow) * SEQ + koff + kt * 64 + slog],
                  vdst + p * 1024);
    }
    __syncthreads();   // vmcnt drained before barrier

    // S^T per key-subtile u: K frags read once, reused for 4 q-sets
#pragma unroll
    for (int u = 0; u < 4; u++) {
      bf16x8 ka0 = *(const bf16x8*)&ksb[(u * 16 + lm) * 64 + xk0];
      bf16x8 ka1 = *(const bf16x8*)&ksb[(u * 16 + lm) * 64 + xk1];
      f32x4 st[4];
#pragma unroll
      for (int s = 0; s < 4; s++) {
        f32x4 z = {0.f, 0.f, 0.f, 0.f};
        z = mfma_bf16(ka0, qb[s][0], z);
        z = mfma_bf16(ka1, qb[s][1], z);
        st[s] = z;
      }
      // static-max softmax + pack P^T
#pragma unroll
      for (int s = 0; s < 4; s++) {
        float p0 = fast_exp2(st[s][0] - 8.0f);
        float p1 = fast_exp2(st[s][1] - 8.0f);
        float p2 = fast_exp2(st[s][2] - 8.0f);
        float p3 = fast_exp2(st[s][3] - 8.0f);
        li[s] += (p0 + p1) + (p2 + p3);
        uint2 pk;
        pk.x = cvt_pk_bf16(p0, p1);
        pk.y = cvt_pk_bf16(p2, p3);
        const int phys = (u * 2 + (lg >> 1)) ^ (lm & 7);
        *(uint2*)&psb[(s * 16 + lm) * 64 + phys * 8 + (lg & 1) * 4] = pk;
      }
    }

    // O^T += V^T @ P^T: V frags read once per (kc,dt), reused for 4 sets
#pragma unroll
    for (int kc = 0; kc < 2; kc++) {
      const int xo = kc ? xk1 : xk0;
      bf16x8 pb[4];
#pragma unroll
      for (int s = 0; s < 4; s++)
        pb[s] = *(const bf16x8*)&psb[(s * 16 + lm) * 64 + xo];
#pragma unroll
      for (int dt = 0; dt < 4; dt++) {
        bf16x8 va = *(const bf16x8*)&vsb[(dt * 16 + lm) * 64 + xo];
#pragma unroll
        for (int s = 0; s < 4; s++)
          o[dt][s] = mfma_bf16(va, pb[s], o[dt][s]);
      }
    }
  }

  // ---- cross-split combine (exact: fixed max -> partials additive) ----
  __syncthreads();                 // all frag reads done; safe to overwrite
  f32x4* ob = shbuf + qh * 1088;   // 16x64 f32x4 + 64 f32x4 of li per q-half
  float*  lb = (float*)(ob + 1024);
  if (ks == 1) {
#pragma unroll
    for (int dt = 0; dt < 4; dt++)
#pragma unroll
      for (int s = 0; s < 4; s++)
        ob[(dt * 4 + s) * 64 + lane] = o[dt][s];
#pragma unroll
    for (int s = 0; s < 4; s++) lb[s * 64 + lane] = li[s];
  }
  __syncthreads();
  if (ks == 0) {
#pragma unroll
    for (int dt = 0; dt < 4; dt++)
#pragma unroll
      for (int s = 0; s < 4; s++)
        o[dt][s] += ob[(dt * 4 + s) * 64 + lane];
#pragma unroll
    for (int s = 0; s < 4; s++) {
      float l = li[s] + lb[s * 64 + lane];
      l += __shfl_xor(l, 16, 64);
      l += __shfl_xor(l, 32, 64);
      const float inv = 1.0f / l;
#pragma unroll
      for (int dt = 0; dt < 4; dt++) {
        uint2 ok;
        ok.x = cvt_pk_bf16(o[dt][s][0] * inv, o[dt][s][1] * inv);
        ok.y = cvt_pk_bf16(o[dt][s][2] * inv, o[dt][s][3] * inv);
        *(uint2*)&out[(size_t)(qrow_base + s * 16 + lm) * DIMC + h * 64 +
                      dt * 16 + lg * 4] = ok;
      }
    }
  }
}

// ---------------------------------------------------------------------------
extern "C" void kernel_launch(void* const* d_in, const int* in_sizes, int n_in,
                              void* d_out, int out_size, void* d_ws, size_t ws_size,
                              hipStream_t stream) {
  const float* x      = (const float*)d_in[0];
  const float* ln1_g  = (const float*)d_in[1];
  const float* ln1_b  = (const float*)d_in[2];
  const float* w_qkv  = (const float*)d_in[3];
  const float* w_proj = (const float*)d_in[4];
  const float* b_proj = (const float*)d_in[5];
  const float* ln2_g  = (const float*)d_in[6];
  const float* ln2_b  = (const float*)d_in[7];
  const float* w1     = (const float*)d_in[8];
  const float* b1     = (const float*)d_in[9];
  const float* w2     = (const float*)d_in[10];
  const float* b2     = (const float*)d_in[11];
  float* out = (float*)d_out;

  char* ws = (char*)d_ws;
  size_t off = 0;
  auto alloc = [&](size_t bytes) { void* p = ws + off; off += (bytes + 255) & ~(size_t)255; return p; };
  unsigned short* wqkvT = (unsigned short*)alloc((size_t)3072 * 1024 * 2);
  unsigned short* wprjT = (unsigned short*)alloc((size_t)1024 * 1024 * 2);
  unsigned short* w1T   = (unsigned short*)alloc((size_t)4096 * 1024 * 2);
  unsigned short* w2T   = (unsigned short*)alloc((size_t)1024 * 4096 * 2);
  unsigned short* hb    = (unsigned short*)alloc((size_t)TOK * 1024 * 2);
  unsigned short* qbuf  = (unsigned short*)alloc((size_t)TOK * 1024 * 2);
  unsigned short* vdb   = (unsigned short*)alloc((size_t)TOK * 1024 * 2);
  unsigned short* attnb = (unsigned short*)alloc((size_t)TOK * 1024 * 2);
  float*          x1    = (float*)         alloc((size_t)TOK * 1024 * 4);
  unsigned short* hidb  = (unsigned short*)alloc((size_t)TOK * 4096 * 2);
  // kT/vT overlay hidb (32MB >= 16MB): attn finishes before MLP1 writes hidb
  unsigned short* kT = hidb;                              // 8 MB
  unsigned short* vT = hidb + (size_t)32 * SEQ * 64;      // 8 MB

  transpose_cast4<<<12288, 256, 0, stream>>>(w_qkv, wqkvT, w_proj, wprjT,
                                             w1, w1T, w2, w2T);
  ln_kernel<<<TOK, 256, 0, stream>>>(x, ln1_g, ln1_b, hb);
  gemm256<0, 3072, 1024, 12><<<192, 512, 0, stream>>>(   // QKV
      hb, wqkvT, nullptr, nullptr, qbuf, kT, vdb);
  v_transpose<<<dim3(SEQ / 64, 32), 256, 0, stream>>>(vdb, vT);
  attn_kernel<<<512, 256, 0, stream>>>(qbuf, kT, vT, attnb);
  gemm_bt<1, 64><<<512, 256, 0, stream>>>(               // proj: gx=16, gy=32
      attnb, wprjT, x1, nullptr, b_proj, x, TOK, 1024, 1024);
  ln_kernel<<<TOK, 256, 0, stream>>>(x1, ln2_g, ln2_b, hb);
  gemm256<2, 4096, 1024, 16><<<256, 512, 0, stream>>>(   // MLP1
      hb, w1T, hidb, b1, nullptr, nullptr, nullptr);
  gemm_bt<1, 64><<<512, 256, 0, stream>>>(               // MLP2: gx=16, gy=32
      hidb, w2T, out, nullptr, b2, x1, TOK, 1024, 4096);
}

// Round 4
// 339.589 us; speedup vs baseline: 1.0416x; 1.0416x over previous
//
#include <hip/hip_runtime.h>
#include <stdint.h>

// ---------------------------------------------------------------------------
// Transformer block: prep(transpose weights + LN1) -> QKV GEMM (routes
// Q*scale / kT / vd) -> v_transpose -> flash attention (static-max softmax,
// fat waves + in-block key-split) -> proj(+res) -> LN2 -> MLP1(GELU) ->
// MLP2(+res). bf16 MFMA 16x16x32, fp32 acc.
// Fragment layouts (learn_hip m89/m91):
//   A-frag:  A[m = lane&15][k = (lane>>4)*8 + j]
//   B-frag:  B[k = (lane>>4)*8 + j][n = lane&15]  (= Bt[n][k])
//   C/D   :  D[m = (lane>>4)*4 + r][n = lane&15]
// R11: 8-phase gemm256 removed — three structurally distinct ports (R1 runtime
// dbuf, R2 static bufs, R3 asm ds_read + clobber-free fences) all landed at
// gemm_bt-level perf; falsified for this loop. All GEMMs are short-K
// latency-bound (~500 TF, MfmaUtil ~21%, Occ ~19%); measured data (MLP2
// TN=64 @564 TF vs MLP1 TN=128 @477 TF) says TN=64 (4 blocks/CU, 2x blocks)
// is the better operating point -> QKV & MLP1 moved to TN=64. transpose_cast4
// and LN1 fused into one prep launch (both memory-bound, independent).
// ---------------------------------------------------------------------------

#define DIMC 1024
#define HIDN 4096
#define SEQ  2048
#define TOK  4096   // B*N = 2*2048

typedef __bf16 bf16x8 __attribute__((ext_vector_type(8)));
typedef float  f32x4  __attribute__((ext_vector_type(4)));
typedef unsigned short ushort8 __attribute__((ext_vector_type(8)));

__device__ inline unsigned short f2bf(float f) {
  union { float f; unsigned u; } v; v.f = f;
  unsigned u = v.u;
  return (unsigned short)((u + 0x7fffu + ((u >> 16) & 1u)) >> 16);  // RNE
}

// HW packed fp32->bf16 (CDNA3+): lo = cvt(a), hi = cvt(b)
__device__ inline unsigned cvt_pk_bf16(float a, float b) {
  unsigned r;
  asm("v_cvt_pk_bf16_f32 %0, %1, %2" : "=v"(r) : "v"(a), "v"(b));
  return r;
}

#if __has_builtin(__builtin_amdgcn_exp2f)
__device__ inline float fast_exp2(float x) { return __builtin_amdgcn_exp2f(x); }
#else
__device__ inline float fast_exp2(float x) { return exp2f(x); }
#endif

__device__ inline f32x4 mfma_bf16(bf16x8 a, bf16x8 b, f32x4 c) {
  return __builtin_amdgcn_mfma_f32_16x16x32_bf16(a, b, c, 0, 0, 0);
}

// async global->LDS, 16B per lane; LDS dest = wave-uniform base + lane*16
typedef const __attribute__((address_space(1))) unsigned int* as1_u32p;
typedef __attribute__((address_space(3))) unsigned int* as3_u32p;
__device__ inline void gload_lds16(const unsigned short* g, unsigned short* l) {
  __builtin_amdgcn_global_load_lds((as1_u32p)(const void*)g, (as3_u32p)(void*)l,
                                   16, 0, 0);
}

// ---------------------------------------------------------------------------
// prep: all 4 weight transposes (w[K][N] fp32 -> wt[N][K] bf16) + LN1, fused.
// bid < 12288: transpose tiles; bid >= 12288: LN1 row (bid - 12288).
// Both memory-bound and independent -> co-scheduling fills the machine.
// ---------------------------------------------------------------------------
__global__ __launch_bounds__(256)
void prep_kernel(const float* __restrict__ wa, unsigned short* __restrict__ ta,
                 const float* __restrict__ wb, unsigned short* __restrict__ tb,
                 const float* __restrict__ wc, unsigned short* __restrict__ tc,
                 const float* __restrict__ wd, unsigned short* __restrict__ td,
                 const float* __restrict__ x, const float* __restrict__ g,
                 const float* __restrict__ bln, unsigned short* __restrict__ out) {
  const int bid = blockIdx.x;
  const int tid = threadIdx.x;
  if (bid < 12288) {
    __shared__ float tile[32][33];
    const float* w; unsigned short* wt; int K, N, bx, by;
    if (bid < 3072)      { w = wa; wt = ta; K = 1024; N = 3072; bx = bid % 96;  by = bid / 96; }
    else if (bid < 4096) { int i = bid - 3072; w = wb; wt = tb; K = 1024; N = 1024; bx = i % 32;  by = i / 32; }
    else if (bid < 8192) { int i = bid - 4096; w = wc; wt = tc; K = 1024; N = 4096; bx = i % 128; by = i / 128; }
    else                 { int i = bid - 8192; w = wd; wt = td; K = 4096; N = 1024; bx = i % 32;  by = i / 32; }
    const int k0 = by * 32;
    const int n0 = bx * 32;
    const int tx = tid & 31;
    const int ty = tid >> 5;  // 0..7
#pragma unroll
    for (int i = 0; i < 4; i++)
      tile[ty + i * 8][tx] = w[(size_t)(k0 + ty + i * 8) * N + n0 + tx];
    __syncthreads();
#pragma unroll
    for (int i = 0; i < 4; i++)
      wt[(size_t)(n0 + ty + i * 8) * K + k0 + tx] = f2bf(tile[tx][ty + i * 8]);
  } else {
    const int row = bid - 12288;
    const float4* xr = (const float4*)&x[(size_t)row * DIMC];
    float4 v = xr[tid];
    float s  = v.x + v.y + v.z + v.w;
    float sq = v.x * v.x + v.y * v.y + v.z * v.z + v.w * v.w;
#pragma unroll
    for (int off = 32; off > 0; off >>= 1) {
      s  += __shfl_xor(s, off, 64);
      sq += __shfl_xor(sq, off, 64);
    }
    __shared__ float red[8];
    if ((tid & 63) == 0) { red[tid >> 6] = s; red[4 + (tid >> 6)] = sq; }
    __syncthreads();
    s  = red[0] + red[1] + red[2] + red[3];
    sq = red[4] + red[5] + red[6] + red[7];
    const float mu  = s * (1.0f / DIMC);
    const float var = sq * (1.0f / DIMC) - mu * mu;
    const float rs  = rsqrtf(var + 1e-5f);
    const int c = tid * 4;
    float vv[4] = {v.x, v.y, v.z, v.w};
#pragma unroll
    for (int j = 0; j < 4; j++)
      out[(size_t)row * DIMC + c + j] = f2bf((vv[j] - mu) * rs * g[c + j] + bln[c + j]);
  }
}

// ---------------------------------------------------------------------------
// LayerNorm: x[rows][1024] fp32 -> out bf16 (used for LN2)
// ---------------------------------------------------------------------------
__global__ __launch_bounds__(256)
void ln_kernel(const float* __restrict__ x, const float* __restrict__ g,
               const float* __restrict__ b, unsigned short* __restrict__ out) {
  const int row = blockIdx.x;
  const int tid = threadIdx.x;
  const float4* xr = (const float4*)&x[(size_t)row * DIMC];
  float4 v = xr[tid];
  float s  = v.x + v.y + v.z + v.w;
  float sq = v.x * v.x + v.y * v.y + v.z * v.z + v.w * v.w;
#pragma unroll
  for (int off = 32; off > 0; off >>= 1) {
    s  += __shfl_xor(s, off, 64);
    sq += __shfl_xor(sq, off, 64);
  }
  __shared__ float red[8];
  if ((tid & 63) == 0) { red[tid >> 6] = s; red[4 + (tid >> 6)] = sq; }
  __syncthreads();
  s  = red[0] + red[1] + red[2] + red[3];
  sq = red[4] + red[5] + red[6] + red[7];
  const float mu  = s * (1.0f / DIMC);
  const float var = sq * (1.0f / DIMC) - mu * mu;
  const float rs  = rsqrtf(var + 1e-5f);
  const int c = tid * 4;
  float vv[4] = {v.x, v.y, v.z, v.w};
#pragma unroll
  for (int j = 0; j < 4; j++)
    out[(size_t)row * DIMC + c + j] = f2bf((vv[j] - mu) * rs * g[c + j] + b[c + j]);
}

// ---------------------------------------------------------------------------
// GEMM: C[M][N] = A[M][K] @ B, Bt[N][K] bf16. 128xTN tile, BK=64, 4 waves.
// 1D grid, XCD decode: bid&7 = XCD owns 4 consecutive y-stripes.
// EPI: 0 = QKV routing epilogue (Q*scale -> qd, K -> kTd, V -> vd dense);
//      1 = +bias+res fp32; 2 = gelu(+bias) bf16
// ---------------------------------------------------------------------------
template <int EPI, int TN>
__global__ __launch_bounds__(256, (TN == 64) ? 4 : 3)
void gemm_bt(const unsigned short* __restrict__ A,
             const unsigned short* __restrict__ Bt,
             float* __restrict__ Cf, unsigned short* __restrict__ Cb,
             const float* __restrict__ bias, const float* __restrict__ res,
             int M, int N, int K,
             unsigned short* __restrict__ qd,
             unsigned short* __restrict__ kTd,
             unsigned short* __restrict__ vd) {
  constexpr int NU = TN / 32;            // B n-tiles per wave
  constexpr int BP = TN / 32;            // B staging passes (32 rows each)
  __shared__ unsigned short As[128 * 64];
  __shared__ unsigned short Bs[TN * 64];
  const int gx  = N / TN;                // x-tiles; gy = M/128 = 32 always
  const int bid = blockIdx.x;
  const int xcd = bid & 7;
  const int lin = bid >> 3;
  const int bx  = lin % gx;
  const int by  = (xcd << 2) + lin / gx;  // 4 y-stripes per XCD
  const int tid  = threadIdx.x;
  const int lane = tid & 63;
  const int wave = tid >> 6;
  const int m0 = by * 128;
  const int n0 = bx * TN;
  const int wm = (wave >> 1) * 64;
  const int wn = (wave & 1) * (TN / 2);
  const int lm = lane & 15;
  const int lg = lane >> 4;
  const int r8 = tid >> 3;     // 0..31 row within pass
  const int c8 = tid & 7;      // phys 16B chunk within 128B row
  const int csrc = ((c8 ^ (r8 & 7)) * 8);  // logical elem offset (swizzled)

  const unsigned short* gA = &A [(size_t)(m0 + r8) * K + csrc];
  const unsigned short* gB = &Bt[(size_t)(n0 + r8) * K + csrc];

  f32x4 acc[4][NU];
#pragma unroll
  for (int t = 0; t < 4; t++)
#pragma unroll
    for (int u = 0; u < NU; u++) acc[t][u] = {0.f, 0.f, 0.f, 0.f};

  const int x0 = (lg ^ (lm & 7)) * 8;        // sub 0 phys chunk offset (elems)
  const int x1 = ((4 + lg) ^ (lm & 7)) * 8;  // sub 1

  for (int k0 = 0; k0 < K; k0 += 64) {
    __syncthreads();                 // prior tile's LDS reads done
#pragma unroll
    for (int p = 0; p < 4; p++)
      gload_lds16(gA + (size_t)p * 32 * K + k0, &As[p * 2048 + wave * 512]);
#pragma unroll
    for (int p = 0; p < BP; p++)
      gload_lds16(gB + (size_t)p * 32 * K + k0, &Bs[p * 2048 + wave * 512]);
    __syncthreads();                 // drains vmcnt before barrier
#pragma unroll
    for (int sub = 0; sub < 2; sub++) {
      const int xo = sub ? x1 : x0;
      bf16x8 af[4], bfr[NU];
#pragma unroll
      for (int t = 0; t < 4; t++)  af[t]  = *(const bf16x8*)&As[(wm + t * 16 + lm) * 64 + xo];
#pragma unroll
      for (int u = 0; u < NU; u++) bfr[u] = *(const bf16x8*)&Bs[(wn + u * 16 + lm) * 64 + xo];
#pragma unroll
      for (int t = 0; t < 4; t++)
#pragma unroll
        for (int u = 0; u < NU; u++)
          acc[t][u] = mfma_bf16(af[t], bfr[u], acc[t][u]);
    }
  }

#pragma unroll
  for (int t = 0; t < 4; t++) {
    const int row = m0 + wm + t * 16 + lg * 4;
#pragma unroll
    for (int u = 0; u < NU; u++) {
      const int col = n0 + wn + u * 16 + lm;
#pragma unroll
      for (int r = 0; r < 4; r++) {
        float v = acc[t][u][r];
        size_t idx = (size_t)(row + r) * N + col;
        if (EPI == 0) {
          // QKV routing: block's col range (TN-wide) is segment-uniform
          const int rr = row + r;
          const int bb = rr >> 11, key = rr & (SEQ - 1);
          if (col < 1024) {
            qd[(size_t)rr * 1024 + col] = f2bf(v * 0.18033688011112042f);
          } else if (col < 2048) {
            const int d = col - 1024, h = d >> 6, dd = d & 63;
            kTd[(((size_t)(bb * 16 + h)) * SEQ + key) * 64 + dd] = f2bf(v);
          } else {
            vd[(size_t)rr * 1024 + (col - 2048)] = f2bf(v);  // dense, coalesced
          }
        } else if (EPI == 1) {
          Cf[idx] = v + bias[col] + res[idx];
        } else {
          float xg = v + bias[col];
          Cb[idx] = f2bf(0.5f * xg * (1.0f + erff(xg * 0.70710678118654752f)));
        }
      }
    }
  }
}

// ---------------------------------------------------------------------------
// V transpose per head: vd[token][1024] -> vT[bh][d][key] (via LDS)
// ---------------------------------------------------------------------------
__global__ __launch_bounds__(256)
void v_transpose(const unsigned short* __restrict__ vd,
                 unsigned short* __restrict__ vT) {
  const int kt = blockIdx.x;
  const int bh = blockIdx.y;
  const int b = bh >> 4, h = bh & 15;
  const int tid = threadIdx.x;
  __shared__ unsigned short tile[64 * 72];
  const int tok = tid >> 2;       // 0..63
  const int ch  = tid & 3;        // chunks ch, ch+4 (8 d each)
  const size_t srow = (size_t)(b * SEQ + kt * 64 + tok) * 1024 + h * 64;
  ushort8 va = *(const ushort8*)&vd[srow + ch * 8];
  ushort8 vb = *(const ushort8*)&vd[srow + 32 + ch * 8];
  *(ushort8*)&tile[tok * 72 + ch * 8] = va;
  *(ushort8*)&tile[tok * 72 + 32 + ch * 8] = vb;
  __syncthreads();
  const int d = tid >> 2;         // 0..63
  ushort8 o0, o1;
#pragma unroll
  for (int j = 0; j < 8; j++) {
    o0[j] = tile[(ch * 8 + j) * 72 + d];
    o1[j] = tile[((ch + 4) * 8 + j) * 72 + d];
  }
  const size_t vdst = ((size_t)bh * 64 + d) * SEQ + kt * 64;
  *(ushort8*)&vT[vdst + ch * 8] = o0;
  *(ushort8*)&vT[vdst + 32 + ch * 8] = o1;
}

// ---------------------------------------------------------------------------
// Flash attention: fat waves + in-block key-split, static-max softmax.
// Block = 256 thr = 4 waves; wave w: ks = w>>1 (keys ks*1024..+1023),
// qh = w&1 (64 q-rows, 4 sets). 16-tile k-loop. After the loop, ks=1 waves
// export o/li via LDS; ks=0 waves add (exactly additive: fixed max) and
// store. Grid 512 (bid&7=XCD -> 4 bh/XCD, kT/vT L2-resident). LDS 64 KB.
// ---------------------------------------------------------------------------
__global__ __launch_bounds__(256, 2)
void attn_kernel(const unsigned short* __restrict__ qbuf,
                 const unsigned short* __restrict__ kT,
                 const unsigned short* __restrict__ vT,
                 unsigned short* __restrict__ out) {
  const int bid = blockIdx.x;
  const int xcd = bid & 7;
  const int lin = bid >> 3;                 // 0..63
  const int bh  = (xcd << 2) + (lin >> 4);  // 4 bh per XCD
  const int qt  = lin & 15;                 // 128-q tile
  const int b  = bh >> 4;
  const int h  = bh & 15;
  const int tid  = threadIdx.x;             // 0..255
  const int lane = tid & 63;
  const int wave = tid >> 6;                // 0..3
  const int ks   = wave >> 1;               // key split
  const int qh   = wave & 1;                // q half
  const int lm = lane & 15;
  const int lg = lane >> 4;

  __shared__ f32x4 shbuf[4096];             // 64 KB, multi-purpose
  unsigned short* Ks = (unsigned short*)shbuf;          // [2][64*64]
  unsigned short* Vs = (unsigned short*)shbuf + 8192;   // [2][64*64]
  unsigned short* Ps = (unsigned short*)shbuf + 16384;  // [4][64*64]

  const int qrow_base = b * SEQ + qt * 128 + qh * 64;
  bf16x8 qb[4][2];  // [set][khalf] B-frag: Q natural (pre-scaled)
#pragma unroll
  for (int s = 0; s < 4; s++)
#pragma unroll
    for (int c = 0; c < 2; c++)
      qb[s][c] = *(const bf16x8*)&qbuf[(size_t)(qrow_base + s * 16 + lm) * 1024 +
                                       h * 64 + c * 32 + lg * 8];

  f32x4 o[4][4];   // [dtile][set]: m = d, n = q
#pragma unroll
  for (int dt = 0; dt < 4; dt++)
#pragma unroll
    for (int s = 0; s < 4; s++) o[dt][s] = {0.f, 0.f, 0.f, 0.f};
  float li[4] = {0.f, 0.f, 0.f, 0.f};

  const unsigned short* kbp = &kT[(size_t)bh * SEQ * 64];
  const unsigned short* vbp = &vT[(size_t)bh * 64 * SEQ];
  const int ts   = tid & 127;                     // id within split pair
  const int srow = ts >> 3;                       // 0..15 (row within pass)
  const int slog = ((ts & 7) ^ (srow & 7)) * 8;   // swizzled source offset
  const int koff = ks * 1024;                     // split key base
  const int xk0 = ((lg)     ^ (lm & 7)) * 8;      // frag phys offsets
  const int xk1 = ((4 + lg) ^ (lm & 7)) * 8;
  unsigned short* ksb = Ks + ks * 4096;
  unsigned short* vsb = Vs + ks * 4096;
  unsigned short* psb = Ps + wave * 4096;
  unsigned short* kdst = ksb + ((ts >> 6) * 512); // wave-uniform + lane*16
  unsigned short* vdst = vsb + ((ts >> 6) * 512);

  for (int kt = 0; kt < 16; kt++) {
    __syncthreads();   // prior tile's frag reads done
#pragma unroll
    for (int p = 0; p < 4; p++) {
      gload_lds16(&kbp[(size_t)(koff + kt * 64 + p * 16 + srow) * 64 + slog],
                  kdst + p * 1024);
      gload_lds16(&vbp[(size_t)(p * 16 + srow) * SEQ + koff + kt * 64 + slog],
                  vdst + p * 1024);
    }
    __syncthreads();   // vmcnt drained before barrier

    // S^T per key-subtile u: K frags read once, reused for 4 q-sets
#pragma unroll
    for (int u = 0; u < 4; u++) {
      bf16x8 ka0 = *(const bf16x8*)&ksb[(u * 16 + lm) * 64 + xk0];
      bf16x8 ka1 = *(const bf16x8*)&ksb[(u * 16 + lm) * 64 + xk1];
      f32x4 st[4];
#pragma unroll
      for (int s = 0; s < 4; s++) {
        f32x4 z = {0.f, 0.f, 0.f, 0.f};
        z = mfma_bf16(ka0, qb[s][0], z);
        z = mfma_bf16(ka1, qb[s][1], z);
        st[s] = z;
      }
      // static-max softmax + pack P^T
#pragma unroll
      for (int s = 0; s < 4; s++) {
        float p0 = fast_exp2(st[s][0] - 8.0f);
        float p1 = fast_exp2(st[s][1] - 8.0f);
        float p2 = fast_exp2(st[s][2] - 8.0f);
        float p3 = fast_exp2(st[s][3] - 8.0f);
        li[s] += (p0 + p1) + (p2 + p3);
        uint2 pk;
        pk.x = cvt_pk_bf16(p0, p1);
        pk.y = cvt_pk_bf16(p2, p3);
        const int phys = (u * 2 + (lg >> 1)) ^ (lm & 7);
        *(uint2*)&psb[(s * 16 + lm) * 64 + phys * 8 + (lg & 1) * 4] = pk;
      }
    }

    // O^T += V^T @ P^T: V frags read once per (kc,dt), reused for 4 sets
#pragma unroll
    for (int kc = 0; kc < 2; kc++) {
      const int xo = kc ? xk1 : xk0;
      bf16x8 pb[4];
#pragma unroll
      for (int s = 0; s < 4; s++)
        pb[s] = *(const bf16x8*)&psb[(s * 16 + lm) * 64 + xo];
#pragma unroll
      for (int dt = 0; dt < 4; dt++) {
        bf16x8 va = *(const bf16x8*)&vsb[(dt * 16 + lm) * 64 + xo];
#pragma unroll
        for (int s = 0; s < 4; s++)
          o[dt][s] = mfma_bf16(va, pb[s], o[dt][s]);
      }
    }
  }

  // ---- cross-split combine (exact: fixed max -> partials additive) ----
  __syncthreads();                 // all frag reads done; safe to overwrite
  f32x4* ob = shbuf + qh * 1088;   // 16x64 f32x4 + 64 f32x4 of li per q-half
  float*  lb = (float*)(ob + 1024);
  if (ks == 1) {
#pragma unroll
    for (int dt = 0; dt < 4; dt++)
#pragma unroll
      for (int s = 0; s < 4; s++)
        ob[(dt * 4 + s) * 64 + lane] = o[dt][s];
#pragma unroll
    for (int s = 0; s < 4; s++) lb[s * 64 + lane] = li[s];
  }
  __syncthreads();
  if (ks == 0) {
#pragma unroll
    for (int dt = 0; dt < 4; dt++)
#pragma unroll
      for (int s = 0; s < 4; s++)
        o[dt][s] += ob[(dt * 4 + s) * 64 + lane];
#pragma unroll
    for (int s = 0; s < 4; s++) {
      float l = li[s] + lb[s * 64 + lane];
      l += __shfl_xor(l, 16, 64);
      l += __shfl_xor(l, 32, 64);
      const float inv = 1.0f / l;
#pragma unroll
      for (int dt = 0; dt < 4; dt++) {
        uint2 ok;
        ok.x = cvt_pk_bf16(o[dt][s][0] * inv, o[dt][s][1] * inv);
        ok.y = cvt_pk_bf16(o[dt][s][2] * inv, o[dt][s][3] * inv);
        *(uint2*)&out[(size_t)(qrow_base + s * 16 + lm) * DIMC + h * 64 +
                      dt * 16 + lg * 4] = ok;
      }
    }
  }
}

// ---------------------------------------------------------------------------
extern "C" void kernel_launch(void* const* d_in, const int* in_sizes, int n_in,
                              void* d_out, int out_size, void* d_ws, size_t ws_size,
                              hipStream_t stream) {
  const float* x      = (const float*)d_in[0];
  const float* ln1_g  = (const float*)d_in[1];
  const float* ln1_b  = (const float*)d_in[2];
  const float* w_qkv  = (const float*)d_in[3];
  const float* w_proj = (const float*)d_in[4];
  const float* b_proj = (const float*)d_in[5];
  const float* ln2_g  = (const float*)d_in[6];
  const float* ln2_b  = (const float*)d_in[7];
  const float* w1     = (const float*)d_in[8];
  const float* b1     = (const float*)d_in[9];
  const float* w2     = (const float*)d_in[10];
  const float* b2     = (const float*)d_in[11];
  float* out = (float*)d_out;

  char* ws = (char*)d_ws;
  size_t off = 0;
  auto alloc = [&](size_t bytes) { void* p = ws + off; off += (bytes + 255) & ~(size_t)255; return p; };
  unsigned short* wqkvT = (unsigned short*)alloc((size_t)3072 * 1024 * 2);
  unsigned short* wprjT = (unsigned short*)alloc((size_t)1024 * 1024 * 2);
  unsigned short* w1T   = (unsigned short*)alloc((size_t)4096 * 1024 * 2);
  unsigned short* w2T   = (unsigned short*)alloc((size_t)1024 * 4096 * 2);
  unsigned short* hb    = (unsigned short*)alloc((size_t)TOK * 1024 * 2);
  unsigned short* qbuf  = (unsigned short*)alloc((size_t)TOK * 1024 * 2);
  unsigned short* vdb   = (unsigned short*)alloc((size_t)TOK * 1024 * 2);
  unsigned short* attnb = (unsigned short*)alloc((size_t)TOK * 1024 * 2);
  float*          x1    = (float*)         alloc((size_t)TOK * 1024 * 4);
  unsigned short* hidb  = (unsigned short*)alloc((size_t)TOK * 4096 * 2);
  // kT/vT overlay hidb (32MB >= 16MB): attn finishes before MLP1 writes hidb
  unsigned short* kT = hidb;                              // 8 MB
  unsigned short* vT = hidb + (size_t)32 * SEQ * 64;      // 8 MB

  prep_kernel<<<12288 + TOK, 256, 0, stream>>>(w_qkv, wqkvT, w_proj, wprjT,
                                               w1, w1T, w2, w2T,
                                               x, ln1_g, ln1_b, hb);
  gemm_bt<0, 64><<<1536, 256, 0, stream>>>(       // QKV: gx=48, gy=32
      hb, wqkvT, nullptr, nullptr, nullptr, nullptr, TOK, 3072, 1024,
      qbuf, kT, vdb);
  v_transpose<<<dim3(SEQ / 64, 32), 256, 0, stream>>>(vdb, vT);
  attn_kernel<<<512, 256, 0, stream>>>(qbuf, kT, vT, attnb);
  gemm_bt<1, 64><<<512, 256, 0, stream>>>(        // proj: gx=16, gy=32
      attnb, wprjT, x1, nullptr, b_proj, x, TOK, 1024, 1024,
      nullptr, nullptr, nullptr);
  ln_kernel<<<TOK, 256, 0, stream>>>(x1, ln2_g, ln2_b, hb);
  gemm_bt<2, 64><<<2048, 256, 0, stream>>>(       // MLP1: gx=64, gy=32
      hb, w1T, nullptr, hidb, b1, nullptr, TOK, 4096, 1024,
      nullptr, nullptr, nullptr);
  gemm_bt<1, 64><<<512, 256, 0, stream>>>(        // MLP2: gx=16, gy=32
      hidb, w2T, out, nullptr, b2, x1, TOK, 1024, 4096,
      nullptr, nullptr, nullptr);
}